// Round 5
// baseline (51.276 us; speedup 1.0000x reference)
//
#include <hip/hip_runtime.h>

// Problem constants: B=256, P=64, D=1024, MARGIN=0.1
constexpr int NB = 256;
constexpr int NP = 64;
constexpr int ND = 1024;
constexpr float MARGIN = 0.1f;

typedef __attribute__((ext_vector_type(8))) short bf16x8;  // 8 bf16 (4 VGPRs)
typedef __attribute__((ext_vector_type(4))) short bf16x4;  // 4 bf16 (2 VGPRs)
typedef __attribute__((ext_vector_type(4))) float f32x4;   // MFMA accumulator

// fp32 -> bf16 round-to-nearest-even (inputs are finite gaussians; no NaN path)
static __device__ inline unsigned short f2bf(float f) {
  unsigned u = __builtin_bit_cast(unsigned, f);
  u += 0x7fffu + ((u >> 16) & 1u);
  return (unsigned short)(u >> 16);
}

static __device__ inline bf16x8 cvt8(float4 a, float4 b) {
  bf16x8 r;
  r[0] = (short)f2bf(a.x); r[1] = (short)f2bf(a.y);
  r[2] = (short)f2bf(a.z); r[3] = (short)f2bf(a.w);
  r[4] = (short)f2bf(b.x); r[5] = (short)f2bf(b.y);
  r[6] = (short)f2bf(b.z); r[7] = (short)f2bf(b.w);
  return r;
}

// ---------------------------------------------------------------------------
// Kernel 0: disFtr fp32 -> bf16, once. 256x1024 elems, 4/thread.
// ---------------------------------------------------------------------------
__global__ __launch_bounds__(256) void cvtB_kernel(
    const float* __restrict__ src, short* __restrict__ dst) {
  const int idx = (blockIdx.x * 256 + threadIdx.x) * 4;
  float4 v = *reinterpret_cast<const float4*>(src + idx);
  bf16x4 r;
  r[0] = (short)f2bf(v.x); r[1] = (short)f2bf(v.y);
  r[2] = (short)f2bf(v.z); r[3] = (short)f2bf(v.w);
  *reinterpret_cast<bf16x4*>(dst + idx) = r;
}

// ---------------------------------------------------------------------------
// Kernel 1: simHalf[ph][i][c] = max_{p in half ph} sum_d imFtr[i][p][d]*disB[c][d]
// grid=(256,2), 512 threads = 8 waves, 2 blocks/CU.
// NEW STRUCTURE (R5): the full 32-row A-half (32x1024 bf16 = 64 KB) is staged
// in LDS ONCE (coalesced 128B-per-row segments, whole burst in flight), ONE
// barrier, then a BARRIER-FREE k-loop: per k-chunk(32) each wave does
// 2 ds_read_b128 (A, XOR-swizzled) + 2 global bf16x8 (B rows, L2-resident)
// + 4 MFMA. No syncs -> compiler pipelines loads arbitrarily deep; 16 waves/CU
// hide LDS/L2 latency. (R4 post-mortem: per-chunk __syncthreads drains
// vmcnt(0) on gfx950, serializing every chunk on full HBM latency.)
// LDS swizzle: element [row][k] at slot (k/8)^(row&7), i.e. short index
// ((k/8)^(row&7))*8 + k%8. Write side uses the same mapping.
// MFMA D layout: row(p-part)=(l>>4)*4+reg, col(c-part)=l&15 (proven R2/R4).
// ---------------------------------------------------------------------------
__global__ __launch_bounds__(512, 4) void simmax_half_kernel(
    const float* __restrict__ imFtr, const short* __restrict__ disB,
    float* __restrict__ simHalf) {
  const int i  = blockIdx.x;
  const int ph = blockIdx.y;
  const int t  = threadIdx.x;
  const int w  = t >> 6;   // wave 0..7
  const int l  = t & 63;
  const int lr = l & 15;   // tile row (A) / tile col (B,D)
  const int lk = l >> 4;   // k-group 0..3

  __shared__ short Asl[32][ND];  // 64 KB, full A-half, bf16, swizzled

  // ---- prologue: stage the whole (i,ph) A-half ----
  {
    const int row = t >> 4;    // 0..31
    const int j   = t & 15;    // 16B-slot group
    const int r7  = row & 7;
    const float* ap = imFtr + ((size_t)i * NP + ph * 32 + row) * ND + j * 8;
    short* wp = &Asl[row][(j ^ r7) * 8];
#pragma unroll
    for (int it = 0; it < 8; ++it) {
      float4 a0 = *reinterpret_cast<const float4*>(ap + it * 128);
      float4 a1 = *reinterpret_cast<const float4*>(ap + it * 128 + 4);
      *reinterpret_cast<bf16x8*>(wp + it * 128) = cvt8(a0, a1);
    }
  }
  __syncthreads();  // the ONLY barrier

  // ---- barrier-free k-loop ----
  f32x4 acc[2][2];  // [pt][ct]
#pragma unroll
  for (int pt = 0; pt < 2; ++pt)
#pragma unroll
    for (int ct = 0; ct < 2; ++ct)
#pragma unroll
      for (int r = 0; r < 4; ++r) acc[pt][ct][r] = 0.0f;

  const short* bp0 = disB + (size_t)(w * 32 + lr) * ND + lk * 8;
  const short* bp1 = bp0 + (size_t)16 * ND;
  const int r7a = lr & 7;  // (pt*16+lr)&7 == lr&7

#pragma unroll 4
  for (int kc = 0; kc < 32; ++kc) {
    bf16x8 b0 = *reinterpret_cast<const bf16x8*>(bp0 + kc * 32);
    bf16x8 b1 = *reinterpret_cast<const bf16x8*>(bp1 + kc * 32);
    const int s0 = ((kc * 4 + lk) ^ r7a) * 8;
    bf16x8 a0 = *reinterpret_cast<const bf16x8*>(&Asl[lr][s0]);
    bf16x8 a1 = *reinterpret_cast<const bf16x8*>(&Asl[16 + lr][s0]);
    acc[0][0] = __builtin_amdgcn_mfma_f32_16x16x32_bf16(a0, b0, acc[0][0], 0, 0, 0);
    acc[0][1] = __builtin_amdgcn_mfma_f32_16x16x32_bf16(a0, b1, acc[0][1], 0, 0, 0);
    acc[1][0] = __builtin_amdgcn_mfma_f32_16x16x32_bf16(a1, b0, acc[1][0], 0, 0, 0);
    acc[1][1] = __builtin_amdgcn_mfma_f32_16x16x32_bf16(a1, b1, acc[1][1], 0, 0, 0);
  }

  // max over p-half: 8 per-lane values (2 pt x 4 r), then across k-groups
#pragma unroll
  for (int ct = 0; ct < 2; ++ct) {
    float m = acc[0][ct][0];
#pragma unroll
    for (int pt = 0; pt < 2; ++pt)
#pragma unroll
      for (int r = 0; r < 4; ++r) m = fmaxf(m, acc[pt][ct][r]);
    m = fmaxf(m, __shfl_xor(m, 16));
    m = fmaxf(m, __shfl_xor(m, 32));
    if (l < 16)
      simHalf[((size_t)ph * NB + i) * NB + w * 32 + ct * 16 + l] = m;
  }
}

// ---------------------------------------------------------------------------
// Fallback simmax (fused cvt, needs only 259 KB ws). grid=256, 512 thr.
// ---------------------------------------------------------------------------
__global__ __launch_bounds__(512) void simmax_fallback_kernel(
    const float* __restrict__ imFtr, const float* __restrict__ disFtr,
    float* __restrict__ simMax) {
  const int i  = blockIdx.x;
  const int t  = threadIdx.x;
  const int w  = t >> 6;
  const int l  = t & 63;
  const int lr = l & 15;
  const int lk = l >> 4;

  __shared__ short Asl[NP][64];

  f32x4 acc[4][2];
#pragma unroll
  for (int pt = 0; pt < 4; ++pt)
#pragma unroll
    for (int ct = 0; ct < 2; ++ct)
#pragma unroll
      for (int r = 0; r < 4; ++r) acc[pt][ct][r] = 0.0f;

  const int ar  = t >> 3;
  const int aks = t & 7;
  const float* ap = imFtr + (size_t)i * NP * ND + (size_t)ar * ND + aks * 8;
  const int wslot = ((aks ^ (ar & 7)) * 8);
  float4 av0 = *reinterpret_cast<const float4*>(ap);
  float4 av1 = *reinterpret_cast<const float4*>(ap + 4);

  const float* bp0 = disFtr + (size_t)(w * 32 + lr) * ND + lk * 8;
  const float* bp1 = disFtr + (size_t)(w * 32 + 16 + lr) * ND + lk * 8;

  for (int kc = 0; kc < 16; ++kc) {
    const int kbase = kc * 64;
    float4 bld[2][2][2];
#pragma unroll
    for (int ks = 0; ks < 2; ++ks) {
      const int ko = kbase + ks * 32;
      bld[ks][0][0] = *reinterpret_cast<const float4*>(bp0 + ko);
      bld[ks][0][1] = *reinterpret_cast<const float4*>(bp0 + ko + 4);
      bld[ks][1][0] = *reinterpret_cast<const float4*>(bp1 + ko);
      bld[ks][1][1] = *reinterpret_cast<const float4*>(bp1 + ko + 4);
    }
    __syncthreads();
    *reinterpret_cast<bf16x8*>(&Asl[ar][wslot]) = cvt8(av0, av1);
    if (kc < 15) {
      const float* apn = ap + (kc + 1) * 64;
      av0 = *reinterpret_cast<const float4*>(apn);
      av1 = *reinterpret_cast<const float4*>(apn + 4);
    }
    __syncthreads();

#pragma unroll
    for (int ks = 0; ks < 2; ++ks) {
      bf16x8 bfr0 = cvt8(bld[ks][0][0], bld[ks][0][1]);
      bf16x8 bfr1 = cvt8(bld[ks][1][0], bld[ks][1][1]);
#pragma unroll
      for (int pt = 0; pt < 4; ++pt) {
        const int row  = pt * 16 + lr;
        const int slot = (((ks * 4 + lk) ^ (row & 7)) * 8);
        bf16x8 afr = *reinterpret_cast<const bf16x8*>(&Asl[row][slot]);
        acc[pt][0] = __builtin_amdgcn_mfma_f32_16x16x32_bf16(afr, bfr0, acc[pt][0], 0, 0, 0);
        acc[pt][1] = __builtin_amdgcn_mfma_f32_16x16x32_bf16(afr, bfr1, acc[pt][1], 0, 0, 0);
      }
    }
  }

#pragma unroll
  for (int ct = 0; ct < 2; ++ct) {
    float m = acc[0][ct][0];
#pragma unroll
    for (int pt = 0; pt < 4; ++pt)
#pragma unroll
      for (int r = 0; r < 4; ++r) m = fmaxf(m, acc[pt][ct][r]);
    m = fmaxf(m, __shfl_xor(m, 16));
    m = fmaxf(m, __shfl_xor(m, 32));
    if (l < 16) simMax[(size_t)i * NB + w * 32 + ct * 16 + l] = m;
  }
}

// ---------------------------------------------------------------------------
// Kernel 2: per-row partial sums {mask count, loss_it, loss_ti}.
// Takes two simMax buffers and maxes them (same pointer twice for non-split).
// ---------------------------------------------------------------------------
__global__ __launch_bounds__(256) void loss_kernel(
    const float* __restrict__ sh0, const float* __restrict__ sh1,
    const int* __restrict__ lbl, float* __restrict__ partial) {
  const int i = blockIdx.x;
  const int j = threadIdx.x;
  __shared__ float posi_sh;
  __shared__ float red[3][4];

  float s = fmaxf(sh0[(size_t)i * NB + j], sh1[(size_t)i * NB + j]);
  if (j == i) posi_sh = s;
  __syncthreads();
  const float posi = posi_sh;
  const float posj = fmaxf(sh0[(size_t)j * NB + j], sh1[(size_t)j * NB + j]);

  const float msk = (lbl[i] != lbl[j]) ? 1.0f : 0.0f;
  float c  = msk;
  float l1 = msk * fmaxf(s - posi + MARGIN, 0.0f);
  float l2 = msk * fmaxf(s - posj + MARGIN, 0.0f);
#pragma unroll
  for (int o = 32; o > 0; o >>= 1) {
    c  += __shfl_down(c, o);
    l1 += __shfl_down(l1, o);
    l2 += __shfl_down(l2, o);
  }
  const int w = j >> 6;
  if ((j & 63) == 0) { red[0][w] = c; red[1][w] = l1; red[2][w] = l2; }
  __syncthreads();
  if (j == 0) {
    partial[i * 3 + 0] = red[0][0] + red[0][1] + red[0][2] + red[0][3];
    partial[i * 3 + 1] = red[1][0] + red[1][1] + red[1][2] + red[1][3];
    partial[i * 3 + 2] = red[2][0] + red[2][1] + red[2][2] + red[2][3];
  }
}

// ---------------------------------------------------------------------------
// Kernel 3: final reduction over 256 row-partials -> loss scalar.
// ---------------------------------------------------------------------------
__global__ __launch_bounds__(256) void finalize_kernel(
    const float* __restrict__ partial, float* __restrict__ out) {
  const int t = threadIdx.x;
  __shared__ float red[3][4];
  float c  = partial[t * 3 + 0];
  float l1 = partial[t * 3 + 1];
  float l2 = partial[t * 3 + 2];
#pragma unroll
  for (int o = 32; o > 0; o >>= 1) {
    c  += __shfl_down(c, o);
    l1 += __shfl_down(l1, o);
    l2 += __shfl_down(l2, o);
  }
  const int w = t >> 6;
  if ((t & 63) == 0) { red[0][w] = c; red[1][w] = l1; red[2][w] = l2; }
  __syncthreads();
  if (t == 0) {
    float cs  = red[0][0] + red[0][1] + red[0][2] + red[0][3];
    float l1s = red[1][0] + red[1][1] + red[1][2] + red[1][3];
    float l2s = red[2][0] + red[2][1] + red[2][2] + red[2][3];
    float loss = l1s / cs;                   // reference divides unconditionally
    loss += (cs > 0.0f) ? (l2s / cs) : 0.0f; // guarded second term, as in ref
    out[0] = loss;
  }
}

extern "C" void kernel_launch(void* const* d_in, const int* in_sizes, int n_in,
                              void* d_out, int out_size, void* d_ws, size_t ws_size,
                              hipStream_t stream) {
  (void)in_sizes; (void)n_in; (void)out_size;
  const float* imFtr  = (const float*)d_in[0];
  const float* disFtr = (const float*)d_in[1];
  const int*   lbl    = (const int*)d_in[2];
  float* out = (float*)d_out;

  const size_t disB_bytes = (size_t)NB * ND * sizeof(short);      // 512 KB
  const size_t half_bytes = (size_t)NB * NB * sizeof(float);      // 256 KB
  const size_t need = disB_bytes + 2 * half_bytes + 3 * NB * sizeof(float);

  if (ws_size >= need) {
    short* disB    = (short*)d_ws;
    float* simHalf = (float*)((char*)d_ws + disB_bytes);          // [2][NB][NB]
    float* partial = (float*)((char*)d_ws + disB_bytes + 2 * half_bytes);

    cvtB_kernel<<<dim3(NB), dim3(256), 0, stream>>>(disFtr, disB);
    simmax_half_kernel<<<dim3(NB, 2), dim3(512), 0, stream>>>(imFtr, disB, simHalf);
    loss_kernel<<<dim3(NB), dim3(256), 0, stream>>>(simHalf, simHalf + (size_t)NB * NB,
                                                    lbl, partial);
    finalize_kernel<<<dim3(1), dim3(256), 0, stream>>>(partial, out);
  } else {
    float* simMax  = (float*)d_ws;                                // 256 KB
    float* partial = (float*)((char*)d_ws + (size_t)NB * NB * 4);
    simmax_fallback_kernel<<<dim3(NB), dim3(512), 0, stream>>>(imFtr, disFtr, simMax);
    loss_kernel<<<dim3(NB), dim3(256), 0, stream>>>(simMax, simMax, lbl, partial);
    finalize_kernel<<<dim3(1), dim3(256), 0, stream>>>(partial, out);
  }
}

// Round 6
// 36.624 us; speedup vs baseline: 1.4000x; 1.4000x over previous
//
#include <hip/hip_runtime.h>

// Problem constants: B=256, P=64, D=1024, MARGIN=0.1
constexpr int NB = 256;
constexpr int NP = 64;
constexpr int ND = 1024;
constexpr float MARGIN = 0.1f;

typedef __attribute__((ext_vector_type(8))) short bf16x8;  // 8 bf16 (4 VGPRs)
typedef __attribute__((ext_vector_type(4))) short bf16x4;  // 4 bf16 (2 VGPRs)
typedef __attribute__((ext_vector_type(4))) float f32x4;   // MFMA accumulator

// fp32 -> bf16 round-to-nearest-even (inputs are finite gaussians; no NaN path)
static __device__ inline unsigned short f2bf(float f) {
  unsigned u = __builtin_bit_cast(unsigned, f);
  u += 0x7fffu + ((u >> 16) & 1u);
  return (unsigned short)(u >> 16);
}

static __device__ inline bf16x8 cvt8(float4 a, float4 b) {
  bf16x8 r;
  r[0] = (short)f2bf(a.x); r[1] = (short)f2bf(a.y);
  r[2] = (short)f2bf(a.z); r[3] = (short)f2bf(a.w);
  r[4] = (short)f2bf(b.x); r[5] = (short)f2bf(b.y);
  r[6] = (short)f2bf(b.z); r[7] = (short)f2bf(b.w);
  return r;
}

static __device__ inline bf16x4 cvt4(float4 a) {
  bf16x4 r;
  r[0] = (short)f2bf(a.x); r[1] = (short)f2bf(a.y);
  r[2] = (short)f2bf(a.z); r[3] = (short)f2bf(a.w);
  return r;
}

// ---------------------------------------------------------------------------
// Kernel 0: disFtr fp32 -> bf16, once. 256x1024 elems, 4/thread.
// ---------------------------------------------------------------------------
__global__ __launch_bounds__(256) void cvtB_kernel(
    const float* __restrict__ src, short* __restrict__ dst) {
  const int idx = (blockIdx.x * 256 + threadIdx.x) * 4;
  float4 v = *reinterpret_cast<const float4*>(src + idx);
  *reinterpret_cast<bf16x4*>(dst + idx) = cvt4(v);
}

// ---------------------------------------------------------------------------
// Kernel 1 (R6): simMax[i][c] = max_p sum_d imFtr[i][p][d]*disB[c][d]
// grid=256 (one block per image, 1 block/CU), 512 threads = 8 waves.
// Wave w owns ALL 64 p-rows x 32 c-cols [w*32, w*32+32).
// K is processed in 4 chunks of 256, A (64x256 bf16 = 32 KB) double-buffered
// in LDS. Per chunk: issue next chunk's A global loads + this chunk's 2nd-half
// B loads FIRST (>=1 chunk / half-chunk of lead -> latency amortized; this is
// the fix for R2/R4/R5's ~845 cyc/iter load-to-use serialization), then
// 8 k-iters of {4 ds_read_b128 + 8 MFMA}, then cvt+write next A chunk, then
// ONE barrier. B prefetch is half-chunk ping-pong in named registers (static
// indices only -> stays in VGPRs).
// LDS swizzle: 8-k group G of row r lives at slot (G ^ (r&7)) -> b128
// reads/writes conflict-free.  MFMA D: row=(l>>4)*4+reg, col=l&15 (proven).
// ---------------------------------------------------------------------------
__global__ __launch_bounds__(512) void simmax_kernel(
    const float* __restrict__ imFtr, const short* __restrict__ disB,
    float* __restrict__ simMax) {
  const int i  = blockIdx.x;
  const int t  = threadIdx.x;
  const int w  = t >> 6;   // wave 0..7
  const int l  = t & 63;
  const int lr = l & 15;   // tile row (A) / tile col (B,D)
  const int lk = l >> 4;   // 8-k group 0..3
  const int r7 = lr & 7;   // (pt*16+lr)&7 for every pt

  __shared__ short Asl[2][NP][256];  // 64 KB: double-buffered A k-chunk (bf16)

  f32x4 acc[4][2];  // [pt 0..3][ct 0..1]
#pragma unroll
  for (int pt = 0; pt < 4; ++pt)
#pragma unroll
    for (int ct = 0; ct < 2; ++ct)
#pragma unroll
      for (int r = 0; r < 4; ++r) acc[pt][ct][r] = 0.0f;

  // --- A staging mapping: thread t -> row ar, 8 x float4 at 128B-stride ---
  // load g covers k-floats aj*4 + g*32 .. +3  (per-instr wave pattern:
  // 8 rows x 128B contiguous -> fully coalesced)
  const int ar  = t >> 3;        // 0..63
  const int aj  = t & 7;         // 0..7
  const int ar7 = ar & 7;
  const float* abase = imFtr + ((size_t)i * NP + ar) * ND + aj * 4;

  // --- B pointers: wave cols w*32 + ct*16 + lr, k-offset lk*8 ---
  const short* bp0 = disB + (size_t)(w * 32 + lr) * ND + lk * 8;
  const short* bp1 = bp0 + (size_t)16 * ND;

  bf16x8 bfr[4][2], bnx[4][2];
  float4 areg[8];

#define LOAD_B(DST, KC)                                                      \
  _Pragma("unroll")                                                          \
  for (int kk = 0; kk < 4; ++kk) {                                           \
    DST[kk][0] = *reinterpret_cast<const bf16x8*>(bp0 + ((KC) + kk) * 32);   \
    DST[kk][1] = *reinterpret_cast<const bf16x8*>(bp1 + ((KC) + kk) * 32);   \
  }

#define STAGE_LOAD(C)                                                        \
  _Pragma("unroll")                                                          \
  for (int g = 0; g < 8; ++g)                                                \
    areg[g] = *reinterpret_cast<const float4*>(abase + (C) * 256 + g * 32);

#define STAGE_WRITE(BUF)                                                     \
  _Pragma("unroll")                                                          \
  for (int g = 0; g < 8; ++g) {                                              \
    const int Gl = g * 4 + (aj >> 1);                                        \
    const int sl = (Gl ^ ar7) * 8 + (aj & 1) * 4;                            \
    *reinterpret_cast<bf16x4*>(&Asl[BUF][ar][sl]) = cvt4(areg[g]);           \
  }

#define COMPUTE_QUARTER(BQ, GBASE)                                           \
  _Pragma("unroll")                                                          \
  for (int kk = 0; kk < 4; ++kk) {                                           \
    const int sl = (((GBASE) + kk * 4 + lk) ^ r7) * 8;                       \
    bf16x8 a0 = *reinterpret_cast<const bf16x8*>(&Asl[cb][lr][sl]);          \
    bf16x8 a1 = *reinterpret_cast<const bf16x8*>(&Asl[cb][16 + lr][sl]);     \
    bf16x8 a2 = *reinterpret_cast<const bf16x8*>(&Asl[cb][32 + lr][sl]);     \
    bf16x8 a3 = *reinterpret_cast<const bf16x8*>(&Asl[cb][48 + lr][sl]);     \
    acc[0][0] = __builtin_amdgcn_mfma_f32_16x16x32_bf16(a0, BQ[kk][0], acc[0][0], 0, 0, 0); \
    acc[0][1] = __builtin_amdgcn_mfma_f32_16x16x32_bf16(a0, BQ[kk][1], acc[0][1], 0, 0, 0); \
    acc[1][0] = __builtin_amdgcn_mfma_f32_16x16x32_bf16(a1, BQ[kk][0], acc[1][0], 0, 0, 0); \
    acc[1][1] = __builtin_amdgcn_mfma_f32_16x16x32_bf16(a1, BQ[kk][1], acc[1][1], 0, 0, 0); \
    acc[2][0] = __builtin_amdgcn_mfma_f32_16x16x32_bf16(a2, BQ[kk][0], acc[2][0], 0, 0, 0); \
    acc[2][1] = __builtin_amdgcn_mfma_f32_16x16x32_bf16(a2, BQ[kk][1], acc[2][1], 0, 0, 0); \
    acc[3][0] = __builtin_amdgcn_mfma_f32_16x16x32_bf16(a3, BQ[kk][0], acc[3][0], 0, 0, 0); \
    acc[3][1] = __builtin_amdgcn_mfma_f32_16x16x32_bf16(a3, BQ[kk][1], acc[3][1], 0, 0, 0); \
  }

  // ---- prologue: B half0 of chunk 0 + A chunk 0 ----
  LOAD_B(bfr, 0);
  STAGE_LOAD(0);
  STAGE_WRITE(0);
  __syncthreads();

#pragma unroll
  for (int c = 0; c < 4; ++c) {
    const int cb = c & 1;
    LOAD_B(bnx, c * 8 + 4);        // this chunk's 2nd half (consumed below)
    if (c < 3) STAGE_LOAD(c + 1);  // next A chunk (lands during compute)
    COMPUTE_QUARTER(bfr, 0);
    if (c < 3) LOAD_B(bfr, (c + 1) * 8);  // next chunk's 1st half
    COMPUTE_QUARTER(bnx, 16);
    if (c < 3) {
      STAGE_WRITE(cb ^ 1);         // different LDS buffer: no pre-barrier needed
      __syncthreads();             // one barrier per chunk
    }
  }

#undef LOAD_B
#undef STAGE_LOAD
#undef STAGE_WRITE
#undef COMPUTE_QUARTER

  // ---- epilogue: max over all 64 p, then store ----
#pragma unroll
  for (int ct = 0; ct < 2; ++ct) {
    float m = acc[0][ct][0];
#pragma unroll
    for (int pt = 0; pt < 4; ++pt)
#pragma unroll
      for (int r = 0; r < 4; ++r) m = fmaxf(m, acc[pt][ct][r]);
    m = fmaxf(m, __shfl_xor(m, 16));
    m = fmaxf(m, __shfl_xor(m, 32));
    if (l < 16) simMax[(size_t)i * NB + w * 32 + ct * 16 + lr] = m;
  }
}

// ---------------------------------------------------------------------------
// Fallback simmax (proven R2 path, fused cvt, needs only 259 KB ws).
// ---------------------------------------------------------------------------
__global__ __launch_bounds__(512) void simmax_fallback_kernel(
    const float* __restrict__ imFtr, const float* __restrict__ disFtr,
    float* __restrict__ simMax) {
  const int i  = blockIdx.x;
  const int t  = threadIdx.x;
  const int w  = t >> 6;
  const int l  = t & 63;
  const int lr = l & 15;
  const int lk = l >> 4;

  __shared__ short Asl[NP][64];

  f32x4 acc[4][2];
#pragma unroll
  for (int pt = 0; pt < 4; ++pt)
#pragma unroll
    for (int ct = 0; ct < 2; ++ct)
#pragma unroll
      for (int r = 0; r < 4; ++r) acc[pt][ct][r] = 0.0f;

  const int ar  = t >> 3;
  const int aks = t & 7;
  const float* ap = imFtr + (size_t)i * NP * ND + (size_t)ar * ND + aks * 8;
  const int wslot = ((aks ^ (ar & 7)) * 8);
  float4 av0 = *reinterpret_cast<const float4*>(ap);
  float4 av1 = *reinterpret_cast<const float4*>(ap + 4);

  const float* bp0 = disFtr + (size_t)(w * 32 + lr) * ND + lk * 8;
  const float* bp1 = disFtr + (size_t)(w * 32 + 16 + lr) * ND + lk * 8;

  for (int kc = 0; kc < 16; ++kc) {
    const int kbase = kc * 64;
    float4 bld[2][2][2];
#pragma unroll
    for (int ks = 0; ks < 2; ++ks) {
      const int ko = kbase + ks * 32;
      bld[ks][0][0] = *reinterpret_cast<const float4*>(bp0 + ko);
      bld[ks][0][1] = *reinterpret_cast<const float4*>(bp0 + ko + 4);
      bld[ks][1][0] = *reinterpret_cast<const float4*>(bp1 + ko);
      bld[ks][1][1] = *reinterpret_cast<const float4*>(bp1 + ko + 4);
    }
    __syncthreads();
    *reinterpret_cast<bf16x8*>(&Asl[ar][wslot]) = cvt8(av0, av1);
    if (kc < 15) {
      const float* apn = ap + (kc + 1) * 64;
      av0 = *reinterpret_cast<const float4*>(apn);
      av1 = *reinterpret_cast<const float4*>(apn + 4);
    }
    __syncthreads();

#pragma unroll
    for (int ks = 0; ks < 2; ++ks) {
      bf16x8 bfr0 = cvt8(bld[ks][0][0], bld[ks][0][1]);
      bf16x8 bfr1 = cvt8(bld[ks][1][0], bld[ks][1][1]);
#pragma unroll
      for (int pt = 0; pt < 4; ++pt) {
        const int row  = pt * 16 + lr;
        const int slot = (((ks * 4 + lk) ^ (row & 7)) * 8);
        bf16x8 afr = *reinterpret_cast<const bf16x8*>(&Asl[row][slot]);
        acc[pt][0] = __builtin_amdgcn_mfma_f32_16x16x32_bf16(afr, bfr0, acc[pt][0], 0, 0, 0);
        acc[pt][1] = __builtin_amdgcn_mfma_f32_16x16x32_bf16(afr, bfr1, acc[pt][1], 0, 0, 0);
      }
    }
  }

#pragma unroll
  for (int ct = 0; ct < 2; ++ct) {
    float m = acc[0][ct][0];
#pragma unroll
    for (int pt = 0; pt < 4; ++pt)
#pragma unroll
      for (int r = 0; r < 4; ++r) m = fmaxf(m, acc[pt][ct][r]);
    m = fmaxf(m, __shfl_xor(m, 16));
    m = fmaxf(m, __shfl_xor(m, 32));
    if (l < 16) simMax[(size_t)i * NB + w * 32 + ct * 16 + l] = m;
  }
}

// ---------------------------------------------------------------------------
// Kernel 2: per-row partial sums {mask count, loss_it, loss_ti}.
// ---------------------------------------------------------------------------
__global__ __launch_bounds__(256) void loss_kernel(
    const float* __restrict__ simMax, const int* __restrict__ lbl,
    float* __restrict__ partial) {
  const int i = blockIdx.x;
  const int j = threadIdx.x;
  __shared__ float posi_sh;
  __shared__ float red[3][4];

  float s = simMax[(size_t)i * NB + j];
  if (j == i) posi_sh = s;
  __syncthreads();
  const float posi = posi_sh;
  const float posj = simMax[(size_t)j * NB + j];

  const float msk = (lbl[i] != lbl[j]) ? 1.0f : 0.0f;
  float c  = msk;
  float l1 = msk * fmaxf(s - posi + MARGIN, 0.0f);
  float l2 = msk * fmaxf(s - posj + MARGIN, 0.0f);
#pragma unroll
  for (int o = 32; o > 0; o >>= 1) {
    c  += __shfl_down(c, o);
    l1 += __shfl_down(l1, o);
    l2 += __shfl_down(l2, o);
  }
  const int w = j >> 6;
  if ((j & 63) == 0) { red[0][w] = c; red[1][w] = l1; red[2][w] = l2; }
  __syncthreads();
  if (j == 0) {
    partial[i * 3 + 0] = red[0][0] + red[0][1] + red[0][2] + red[0][3];
    partial[i * 3 + 1] = red[1][0] + red[1][1] + red[1][2] + red[1][3];
    partial[i * 3 + 2] = red[2][0] + red[2][1] + red[2][2] + red[2][3];
  }
}

// ---------------------------------------------------------------------------
// Kernel 3: final reduction over 256 row-partials -> loss scalar.
// ---------------------------------------------------------------------------
__global__ __launch_bounds__(256) void finalize_kernel(
    const float* __restrict__ partial, float* __restrict__ out) {
  const int t = threadIdx.x;
  __shared__ float red[3][4];
  float c  = partial[t * 3 + 0];
  float l1 = partial[t * 3 + 1];
  float l2 = partial[t * 3 + 2];
#pragma unroll
  for (int o = 32; o > 0; o >>= 1) {
    c  += __shfl_down(c, o);
    l1 += __shfl_down(l1, o);
    l2 += __shfl_down(l2, o);
  }
  const int w = t >> 6;
  if ((t & 63) == 0) { red[0][w] = c; red[1][w] = l1; red[2][w] = l2; }
  __syncthreads();
  if (t == 0) {
    float cs  = red[0][0] + red[0][1] + red[0][2] + red[0][3];
    float l1s = red[1][0] + red[1][1] + red[1][2] + red[1][3];
    float l2s = red[2][0] + red[2][1] + red[2][2] + red[2][3];
    float loss = l1s / cs;                   // reference divides unconditionally
    loss += (cs > 0.0f) ? (l2s / cs) : 0.0f; // guarded second term, as in ref
    out[0] = loss;
  }
}

extern "C" void kernel_launch(void* const* d_in, const int* in_sizes, int n_in,
                              void* d_out, int out_size, void* d_ws, size_t ws_size,
                              hipStream_t stream) {
  (void)in_sizes; (void)n_in; (void)out_size;
  const float* imFtr  = (const float*)d_in[0];
  const float* disFtr = (const float*)d_in[1];
  const int*   lbl    = (const int*)d_in[2];
  float* out = (float*)d_out;

  const size_t disB_bytes = (size_t)NB * ND * sizeof(short);      // 512 KB
  const size_t sim_bytes  = (size_t)NB * NB * sizeof(float);      // 256 KB
  const size_t need = disB_bytes + sim_bytes + 3 * NB * sizeof(float);

  if (ws_size >= need) {
    short* disB    = (short*)d_ws;
    float* simMax  = (float*)((char*)d_ws + disB_bytes);
    float* partial = (float*)((char*)d_ws + disB_bytes + sim_bytes);

    cvtB_kernel<<<dim3(NB), dim3(256), 0, stream>>>(disFtr, disB);
    simmax_kernel<<<dim3(NB), dim3(512), 0, stream>>>(imFtr, disB, simMax);
    loss_kernel<<<dim3(NB), dim3(256), 0, stream>>>(simMax, lbl, partial);
    finalize_kernel<<<dim3(1), dim3(256), 0, stream>>>(partial, out);
  } else {
    float* simMax  = (float*)d_ws;                                // 256 KB
    float* partial = (float*)((char*)d_ws + (size_t)NB * NB * 4);
    simmax_fallback_kernel<<<dim3(NB), dim3(512), 0, stream>>>(imFtr, disFtr, simMax);
    loss_kernel<<<dim3(NB), dim3(256), 0, stream>>>(simMax, lbl, partial);
    finalize_kernel<<<dim3(1), dim3(256), 0, stream>>>(partial, out);
  }
}

// Round 7
// 34.484 us; speedup vs baseline: 1.4869x; 1.0621x over previous
//
#include <hip/hip_runtime.h>

// Problem constants: B=256, P=64, D=1024, MARGIN=0.1
constexpr int NB = 256;
constexpr int NP = 64;
constexpr int ND = 1024;
constexpr float MARGIN = 0.1f;

typedef __attribute__((ext_vector_type(8))) short bf16x8;  // 8 bf16 (4 VGPRs)
typedef __attribute__((ext_vector_type(4))) short bf16x4;  // 4 bf16 (2 VGPRs)
typedef __attribute__((ext_vector_type(4))) float f32x4;   // MFMA accumulator

// fp32 -> bf16 round-to-nearest-even (inputs are finite gaussians; no NaN path)
static __device__ inline unsigned short f2bf(float f) {
  unsigned u = __builtin_bit_cast(unsigned, f);
  u += 0x7fffu + ((u >> 16) & 1u);
  return (unsigned short)(u >> 16);
}

static __device__ inline bf16x8 cvt8(float4 a, float4 b) {
  bf16x8 r;
  r[0] = (short)f2bf(a.x); r[1] = (short)f2bf(a.y);
  r[2] = (short)f2bf(a.z); r[3] = (short)f2bf(a.w);
  r[4] = (short)f2bf(b.x); r[5] = (short)f2bf(b.y);
  r[6] = (short)f2bf(b.z); r[7] = (short)f2bf(b.w);
  return r;
}

static __device__ inline bf16x4 cvt4(float4 a) {
  bf16x4 r;
  r[0] = (short)f2bf(a.x); r[1] = (short)f2bf(a.y);
  r[2] = (short)f2bf(a.z); r[3] = (short)f2bf(a.w);
  return r;
}

// ---------------------------------------------------------------------------
// Kernel 0: disFtr fp32 -> bf16, once. 256x1024 elems, 4/thread.
// ---------------------------------------------------------------------------
__global__ __launch_bounds__(256) void cvtB_kernel(
    const float* __restrict__ src, short* __restrict__ dst) {
  const int idx = (blockIdx.x * 256 + threadIdx.x) * 4;
  float4 v = *reinterpret_cast<const float4*>(src + idx);
  *reinterpret_cast<bf16x4*>(dst + idx) = cvt4(v);
}

// ---------------------------------------------------------------------------
// Kernel 1 (R7): simMax[i][c] = max_p sum_d imFtr[i][p][d]*disB[c][d]
// grid=256 (1 block/CU), 1024 threads = 16 waves = 4 waves/SIMD (TLP is the
// point: R2..R6 all stalled on L3-class B-load latency with <=2 waves/SIMD).
// Wave w owns all 64 p x 16 c-cols [w*16, w*16+16) -> acc = 16 VGPR, one B
// stream per wave held in a rolling 8-deep register window (static indices),
// each B load issued 8 k-iters (~600+ cyc) ahead of its MFMA.
// A: 4 K-chunks of 256, double-buffered 64 KB LDS; chunk c+1 global loads
// issued at chunk-c top (~2000 cyc lead), cvt+ds_write at chunk end, one
// __syncthreads per chunk.
// LDS swizzle: 16B-slot s = k/8 stored at s ^ (row&15) -> frag reads
// (16 lanes, rows r..r+15, same s) hit 16 distinct slots: conflict-free.
// MFMA D layout (proven R2-R6): p = pt*16 + lk*4 + reg, c = w*16 + lr.
// ---------------------------------------------------------------------------
__global__ __launch_bounds__(1024, 4) void simmax_kernel(
    const float* __restrict__ imFtr, const short* __restrict__ disB,
    float* __restrict__ simMax) {
  const int i  = blockIdx.x;
  const int t  = threadIdx.x;
  const int w  = t >> 6;   // wave 0..15
  const int l  = t & 63;
  const int lr = l & 15;   // tile col (B,D) / within-tile row (A)
  const int lk = l >> 4;   // k-group 0..3

  __shared__ short Asl[2][NP][256];  // 64 KB: double-buffered A k-chunk (bf16)

  f32x4 acc[4];
#pragma unroll
  for (int pt = 0; pt < 4; ++pt)
#pragma unroll
    for (int r = 0; r < 4; ++r) acc[pt][r] = 0.0f;

  // --- A staging mapping: thread t -> row ar (0..63), col-group aj (0..15) ---
  // per g: 16 lanes (same ar) read 16 consecutive float4 = 256B contiguous.
  const int ar = t >> 4;
  const int aj = t & 15;
  const float* abase = imFtr + ((size_t)i * NP + ar) * ND + aj * 4;
  float4 areg[4];

  // --- B: wave col w*16+lr, k-offset lk*8; one bf16x8 per 32-k iter ---
  const short* bp = disB + (size_t)(w * 16 + lr) * ND + lk * 8;
  bf16x8 breg[8];

#define STAGE_LOAD(C)                                                        \
  _Pragma("unroll")                                                          \
  for (int g = 0; g < 4; ++g)                                                \
    areg[g] = *reinterpret_cast<const float4*>(abase + (C) * 256 + g * 64);

#define STAGE_WRITE(BUF)                                                     \
  _Pragma("unroll")                                                          \
  for (int g = 0; g < 4; ++g) {                                              \
    const int s  = g * 8 + (aj >> 1);                                        \
    const int so = (s ^ (ar & 15)) * 8 + (aj & 1) * 4;                       \
    *reinterpret_cast<bf16x4*>(&Asl[BUF][ar][so]) = cvt4(areg[g]);           \
  }

  // ---- prologue: A chunk 0 + B window for iters 0..7 ----
  STAGE_LOAD(0);
#pragma unroll
  for (int j = 0; j < 8; ++j)
    breg[j] = *reinterpret_cast<const bf16x8*>(bp + j * 32);
  STAGE_WRITE(0);
  __syncthreads();

#pragma unroll
  for (int c = 0; c < 4; ++c) {
    const int cb = c & 1;
    if (c < 3) STAGE_LOAD(c + 1);  // next A chunk: ~full chunk of lead
#pragma unroll
    for (int j8 = 0; j8 < 8; ++j8) {
      const int jj = c * 8 + j8;          // global 32-k iter (compile-time)
      const int so = ((j8 * 4 + lk) ^ lr) * 8;
      bf16x8 a0 = *reinterpret_cast<const bf16x8*>(&Asl[cb][lr][so]);
      bf16x8 a1 = *reinterpret_cast<const bf16x8*>(&Asl[cb][16 + lr][so]);
      bf16x8 a2 = *reinterpret_cast<const bf16x8*>(&Asl[cb][32 + lr][so]);
      bf16x8 a3 = *reinterpret_cast<const bf16x8*>(&Asl[cb][48 + lr][so]);
      acc[0] = __builtin_amdgcn_mfma_f32_16x16x32_bf16(a0, breg[j8], acc[0], 0, 0, 0);
      acc[1] = __builtin_amdgcn_mfma_f32_16x16x32_bf16(a1, breg[j8], acc[1], 0, 0, 0);
      acc[2] = __builtin_amdgcn_mfma_f32_16x16x32_bf16(a2, breg[j8], acc[2], 0, 0, 0);
      acc[3] = __builtin_amdgcn_mfma_f32_16x16x32_bf16(a3, breg[j8], acc[3], 0, 0, 0);
      if (jj + 8 < 32)                     // refill window 8 iters ahead
        breg[j8] = *reinterpret_cast<const bf16x8*>(bp + (jj + 8) * 32);
    }
    if (c < 3) {
      STAGE_WRITE(cb ^ 1);  // writes other buffer; prior-chunk readers done at
      __syncthreads();      // the previous barrier -> one barrier per chunk
    }
  }

#undef STAGE_LOAD
#undef STAGE_WRITE

  // ---- epilogue: max over all 64 p for this lane's column ----
  float m = acc[0][0];
#pragma unroll
  for (int pt = 0; pt < 4; ++pt)
#pragma unroll
    for (int r = 0; r < 4; ++r) m = fmaxf(m, acc[pt][r]);
  m = fmaxf(m, __shfl_xor(m, 16));
  m = fmaxf(m, __shfl_xor(m, 32));
  if (l < 16) simMax[(size_t)i * NB + w * 16 + lr] = m;
}

// ---------------------------------------------------------------------------
// Fallback simmax (proven R2 path, fused cvt, needs only 259 KB ws).
// ---------------------------------------------------------------------------
__global__ __launch_bounds__(512) void simmax_fallback_kernel(
    const float* __restrict__ imFtr, const float* __restrict__ disFtr,
    float* __restrict__ simMax) {
  const int i  = blockIdx.x;
  const int t  = threadIdx.x;
  const int w  = t >> 6;
  const int l  = t & 63;
  const int lr = l & 15;
  const int lk = l >> 4;

  __shared__ short Asl[NP][64];

  f32x4 acc[4][2];
#pragma unroll
  for (int pt = 0; pt < 4; ++pt)
#pragma unroll
    for (int ct = 0; ct < 2; ++ct)
#pragma unroll
      for (int r = 0; r < 4; ++r) acc[pt][ct][r] = 0.0f;

  const int ar  = t >> 3;
  const int aks = t & 7;
  const float* ap = imFtr + (size_t)i * NP * ND + (size_t)ar * ND + aks * 8;
  const int wslot = ((aks ^ (ar & 7)) * 8);
  float4 av0 = *reinterpret_cast<const float4*>(ap);
  float4 av1 = *reinterpret_cast<const float4*>(ap + 4);

  const float* bp0 = disFtr + (size_t)(w * 32 + lr) * ND + lk * 8;
  const float* bp1 = disFtr + (size_t)(w * 32 + 16 + lr) * ND + lk * 8;

  for (int kc = 0; kc < 16; ++kc) {
    const int kbase = kc * 64;
    float4 bld[2][2][2];
#pragma unroll
    for (int ks = 0; ks < 2; ++ks) {
      const int ko = kbase + ks * 32;
      bld[ks][0][0] = *reinterpret_cast<const float4*>(bp0 + ko);
      bld[ks][0][1] = *reinterpret_cast<const float4*>(bp0 + ko + 4);
      bld[ks][1][0] = *reinterpret_cast<const float4*>(bp1 + ko);
      bld[ks][1][1] = *reinterpret_cast<const float4*>(bp1 + ko + 4);
    }
    __syncthreads();
    *reinterpret_cast<bf16x8*>(&Asl[ar][wslot]) = cvt8(av0, av1);
    if (kc < 15) {
      const float* apn = ap + (kc + 1) * 64;
      av0 = *reinterpret_cast<const float4*>(apn);
      av1 = *reinterpret_cast<const float4*>(apn + 4);
    }
    __syncthreads();

#pragma unroll
    for (int ks = 0; ks < 2; ++ks) {
      bf16x8 bfr0 = cvt8(bld[ks][0][0], bld[ks][0][1]);
      bf16x8 bfr1 = cvt8(bld[ks][1][0], bld[ks][1][1]);
#pragma unroll
      for (int pt = 0; pt < 4; ++pt) {
        const int row  = pt * 16 + lr;
        const int slot = (((ks * 4 + lk) ^ (row & 7)) * 8);
        bf16x8 afr = *reinterpret_cast<const bf16x8*>(&Asl[row][slot]);
        acc[pt][0] = __builtin_amdgcn_mfma_f32_16x16x32_bf16(afr, bfr0, acc[pt][0], 0, 0, 0);
        acc[pt][1] = __builtin_amdgcn_mfma_f32_16x16x32_bf16(afr, bfr1, acc[pt][1], 0, 0, 0);
      }
    }
  }

#pragma unroll
  for (int ct = 0; ct < 2; ++ct) {
    float m = acc[0][ct][0];
#pragma unroll
    for (int pt = 0; pt < 4; ++pt)
#pragma unroll
      for (int r = 0; r < 4; ++r) m = fmaxf(m, acc[pt][ct][r]);
    m = fmaxf(m, __shfl_xor(m, 16));
    m = fmaxf(m, __shfl_xor(m, 32));
    if (l < 16) simMax[(size_t)i * NB + w * 32 + ct * 16 + l] = m;
  }
}

// ---------------------------------------------------------------------------
// Kernel 2: per-row partial sums {mask count, loss_it, loss_ti}.
// ---------------------------------------------------------------------------
__global__ __launch_bounds__(256) void loss_kernel(
    const float* __restrict__ simMax, const int* __restrict__ lbl,
    float* __restrict__ partial) {
  const int i = blockIdx.x;
  const int j = threadIdx.x;
  __shared__ float posi_sh;
  __shared__ float red[3][4];

  float s = simMax[(size_t)i * NB + j];
  if (j == i) posi_sh = s;
  __syncthreads();
  const float posi = posi_sh;
  const float posj = simMax[(size_t)j * NB + j];

  const float msk = (lbl[i] != lbl[j]) ? 1.0f : 0.0f;
  float c  = msk;
  float l1 = msk * fmaxf(s - posi + MARGIN, 0.0f);
  float l2 = msk * fmaxf(s - posj + MARGIN, 0.0f);
#pragma unroll
  for (int o = 32; o > 0; o >>= 1) {
    c  += __shfl_down(c, o);
    l1 += __shfl_down(l1, o);
    l2 += __shfl_down(l2, o);
  }
  const int w = j >> 6;
  if ((j & 63) == 0) { red[0][w] = c; red[1][w] = l1; red[2][w] = l2; }
  __syncthreads();
  if (j == 0) {
    partial[i * 3 + 0] = red[0][0] + red[0][1] + red[0][2] + red[0][3];
    partial[i * 3 + 1] = red[1][0] + red[1][1] + red[1][2] + red[1][3];
    partial[i * 3 + 2] = red[2][0] + red[2][1] + red[2][2] + red[2][3];
  }
}

// ---------------------------------------------------------------------------
// Kernel 3: final reduction over 256 row-partials -> loss scalar.
// ---------------------------------------------------------------------------
__global__ __launch_bounds__(256) void finalize_kernel(
    const float* __restrict__ partial, float* __restrict__ out) {
  const int t = threadIdx.x;
  __shared__ float red[3][4];
  float c  = partial[t * 3 + 0];
  float l1 = partial[t * 3 + 1];
  float l2 = partial[t * 3 + 2];
#pragma unroll
  for (int o = 32; o > 0; o >>= 1) {
    c  += __shfl_down(c, o);
    l1 += __shfl_down(l1, o);
    l2 += __shfl_down(l2, o);
  }
  const int w = t >> 6;
  if ((t & 63) == 0) { red[0][w] = c; red[1][w] = l1; red[2][w] = l2; }
  __syncthreads();
  if (t == 0) {
    float cs  = red[0][0] + red[0][1] + red[0][2] + red[0][3];
    float l1s = red[1][0] + red[1][1] + red[1][2] + red[1][3];
    float l2s = red[2][0] + red[2][1] + red[2][2] + red[2][3];
    float loss = l1s / cs;                   // reference divides unconditionally
    loss += (cs > 0.0f) ? (l2s / cs) : 0.0f; // guarded second term, as in ref
    out[0] = loss;
  }
}

extern "C" void kernel_launch(void* const* d_in, const int* in_sizes, int n_in,
                              void* d_out, int out_size, void* d_ws, size_t ws_size,
                              hipStream_t stream) {
  (void)in_sizes; (void)n_in; (void)out_size;
  const float* imFtr  = (const float*)d_in[0];
  const float* disFtr = (const float*)d_in[1];
  const int*   lbl    = (const int*)d_in[2];
  float* out = (float*)d_out;

  const size_t disB_bytes = (size_t)NB * ND * sizeof(short);      // 512 KB
  const size_t sim_bytes  = (size_t)NB * NB * sizeof(float);      // 256 KB
  const size_t need = disB_bytes + sim_bytes + 3 * NB * sizeof(float);

  if (ws_size >= need) {
    short* disB    = (short*)d_ws;
    float* simMax  = (float*)((char*)d_ws + disB_bytes);
    float* partial = (float*)((char*)d_ws + disB_bytes + sim_bytes);

    cvtB_kernel<<<dim3(NB), dim3(256), 0, stream>>>(disFtr, disB);
    simmax_kernel<<<dim3(NB), dim3(1024), 0, stream>>>(imFtr, disB, simMax);
    loss_kernel<<<dim3(NB), dim3(256), 0, stream>>>(simMax, lbl, partial);
    finalize_kernel<<<dim3(1), dim3(256), 0, stream>>>(partial, out);
  } else {
    float* simMax  = (float*)d_ws;                                // 256 KB
    float* partial = (float*)((char*)d_ws + (size_t)NB * NB * 4);
    simmax_fallback_kernel<<<dim3(NB), dim3(512), 0, stream>>>(imFtr, disFtr, simMax);
    loss_kernel<<<dim3(NB), dim3(256), 0, stream>>>(simMax, lbl, partial);
    finalize_kernel<<<dim3(1), dim3(256), 0, stream>>>(partial, out);
  }
}